// Round 2
// baseline (253.132 us; speedup 1.0000x reference)
//
#include <hip/hip_runtime.h>
#include <math.h>

#define NN 50000
#define NE 800000
#define DIM 128
#define NH 8
#define HD 16
#define NTILE 3125            // NN/16 exactly
#define TPB 782               // ceil(NTILE/4) tile-groups
#define LROW 136              // LDS row stride in shorts (128 + 8 pad)
#define QVROW 256             // interleaved qv row: 256 shorts = 512 B
#define SCAN_B 196            // ceil(NN/256)

typedef short v8s __attribute__((ext_vector_type(8)));
typedef float v4f __attribute__((ext_vector_type(4)));

__device__ __forceinline__ unsigned short f2b(float f) {
    unsigned u = __float_as_uint(f);
    u = (u + 0x7fffu + ((u >> 16) & 1u)) >> 16;   // round-to-nearest-even
    return (unsigned short)u;
}
__device__ __forceinline__ float blo(unsigned w) { return __uint_as_float(w << 16); }
__device__ __forceinline__ float bhi(unsigned w) { return __uint_as_float(w & 0xffff0000u); }

// immediate-pattern lane swizzle (BitMode): src = ((lane & and) | or) ^ xor, per 32-half
template<int PAT>
__device__ __forceinline__ float swz(float x) {
    return __int_as_float(__builtin_amdgcn_ds_swizzle(__float_as_int(x), PAT));
}

// ---- K0: convert W{q,k,v,o} -> bf16 packed; zero cnt ----
#define NW4 (4 * DIM * DIM / 4)     // 16384 float4 of W
#define NC4 ((NN + 3) / 4)          // 12500 int4 of cnt
__global__ __launch_bounds__(256) void convert_kernel(
    const float* __restrict__ Wq, const float* __restrict__ Wk,
    const float* __restrict__ Wv, const float* __restrict__ Wo,
    unsigned short* __restrict__ Wb, int* __restrict__ cnt)
{
    int i = blockIdx.x * 256 + threadIdx.x;
    if (i < NW4) {
        int mat = i >> 12;            // 4096 float4 per matrix
        int off = i & 4095;
        const float* Wsrc = (mat == 0) ? Wq : (mat == 1) ? Wk : (mat == 2) ? Wv : Wo;
        float4 f = ((const float4*)Wsrc)[off];
        uint2 o;
        o.x = (unsigned)f2b(f.x) | ((unsigned)f2b(f.y) << 16);
        o.y = (unsigned)f2b(f.z) | ((unsigned)f2b(f.w) << 16);
        ((uint2*)(Wb + (size_t)mat * DIM * DIM))[off] = o;
    } else if (i < NW4 + NC4) {
        ((int4*)cnt)[i - NW4] = make_int4(0, 0, 0, 0);
    }
}

// ---- K1: QKV via MFMA, FUSED over the 3 matrices: x is loaded+converted
// ONCE per row-tile (a-fragments persist in regs), W{q,k,v} staged serially
// through one 34.8 KB LDS buffer. Folded edge histogram. ----
__global__ __launch_bounds__(256) void qkv_mfma_kernel(
    const float* __restrict__ x, const unsigned short* __restrict__ Wb,
    const float* __restrict__ bq, const float* __restrict__ bk, const float* __restrict__ bv,
    unsigned short* __restrict__ qvb, unsigned short* __restrict__ kb,
    const int* __restrict__ tgt, int* __restrict__ cnt)
{
    __shared__ unsigned short Wl[DIM * LROW];   // 34816 B
    const int tid = threadIdx.x;
    const int lane = tid & 63;
    const int warp = tid >> 6;
    const int m = lane & 15;
    const int quad = lane >> 4;

    // folded histogram: grid-stride over edges (fire-and-forget atomics)
    const int gsize = TPB * 256;
    for (int e = blockIdx.x * 256 + tid; e < NE; e += gsize)
        atomicAdd(cnt + tgt[e], 1);

    const int rt = blockIdx.x * 4 + warp;
    const int r0 = rt * 16;
    const bool act = (rt < NTILE);

    // load + convert x row-tile ONCE (shared A-operand for q,k,v)
    v8s a[4];
    if (act) {
#pragma unroll
        for (int kt = 0; kt < 4; ++kt) {
            const float4* xr = (const float4*)(x + (size_t)(r0 + m) * DIM + kt * 32 + quad * 8);
            float4 f0 = xr[0], f1 = xr[1];
            v8s t;
            t[0] = (short)f2b(f0.x); t[1] = (short)f2b(f0.y);
            t[2] = (short)f2b(f0.z); t[3] = (short)f2b(f0.w);
            t[4] = (short)f2b(f1.x); t[5] = (short)f2b(f1.y);
            t[6] = (short)f2b(f1.z); t[7] = (short)f2b(f1.w);
            a[kt] = t;
        }
    }

#pragma unroll
    for (int mat = 0; mat < 3; ++mat) {
        if (mat) __syncthreads();        // all reads of Wl done before restage
        const unsigned short* Wg = Wb + (size_t)mat * DIM * DIM;
#pragma unroll
        for (int it = 0; it < 8; ++it) {
            int chunk = it * 256 + tid;           // 0..2047
            int row = chunk >> 4, c8 = chunk & 15;
            *(uint4*)(Wl + row * LROW + c8 * 8) = ((const uint4*)Wg)[chunk];
        }
        __syncthreads();

        if (act) {
            const float* bias_p = (mat == 0) ? bq : (mat == 1) ? bk : bv;
#pragma unroll
            for (int nt = 0; nt < 8; ++nt) {
                v4f c = {0.f, 0.f, 0.f, 0.f};
#pragma unroll
                for (int kt = 0; kt < 4; ++kt) {
                    v8s b = *(const v8s*)(Wl + (nt * 16 + m) * LROW + kt * 32 + quad * 8);
                    c = __builtin_amdgcn_mfma_f32_16x16x32_bf16(a[kt], b, c, 0, 0, 0);
                }
                int col = nt * 16 + m;           // C/D: col = lane&15
                float bias = bias_p[col];
#pragma unroll
                for (int i = 0; i < 4; ++i) {
                    int row = r0 + quad * 4 + i; // C/D: row = quad*4 + reg
                    unsigned short val = f2b(c[i] + bias);
                    if (mat == 1) {
                        kb[(size_t)row * DIM + col] = val;
                    } else {
                        int pos = (col >> 1) * 4 + (col & 1) + ((mat == 2) ? 2 : 0);
                        qvb[(size_t)row * QVROW + pos] = val;
                    }
                }
            }
        }
    }
}

// ---- K2: per-block (256-elem) local exclusive scan + block sums ----
__global__ __launch_bounds__(256) void scan1_kernel(
    const int* __restrict__ cnt, int* __restrict__ off, int* __restrict__ bsum)
{
    __shared__ int ws4[4];
    const int tid = threadIdx.x, lane = tid & 63, wid = tid >> 6;
    int i = blockIdx.x * 256 + tid;
    int v0 = (i < NN) ? cnt[i] : 0;
    int incl = v0;
#pragma unroll
    for (int d = 1; d < 64; d <<= 1) {
        int t = __shfl_up(incl, d);
        if (lane >= d) incl += t;
    }
    if (lane == 63) ws4[wid] = incl;
    __syncthreads();
    int wexcl = 0;
#pragma unroll
    for (int t = 0; t < 3; ++t) if (t < wid) wexcl += ws4[t];
    if (i < NN) off[i] = wexcl + incl - v0;
    if (tid == 255) bsum[blockIdx.x] = wexcl + incl;
}

// ---- K3: each block scans all 196 block sums (redundantly), adds its own
// base to off, inits cursor; last block writes off[NN] = total. ----
__global__ __launch_bounds__(256) void scan23_kernel(
    const int* __restrict__ bsum, int* __restrict__ off, int* __restrict__ cursor)
{
    __shared__ int ws4[4];
    __shared__ int base_s, total_s;
    const int tid = threadIdx.x, lane = tid & 63, wid = tid >> 6;
    int v0 = (tid < SCAN_B) ? bsum[tid] : 0;
    int incl = v0;
#pragma unroll
    for (int d = 1; d < 64; d <<= 1) {
        int t = __shfl_up(incl, d);
        if (lane >= d) incl += t;
    }
    if (lane == 63) ws4[wid] = incl;
    __syncthreads();
    int wexcl = 0;
#pragma unroll
    for (int t = 0; t < 3; ++t) if (t < wid) wexcl += ws4[t];
    int excl = wexcl + incl - v0;
    if (tid == blockIdx.x) base_s = excl;
    if (tid == SCAN_B - 1) total_s = excl + v0;
    __syncthreads();
    int i = blockIdx.x * 256 + tid;
    if (i < NN) {
        int t = off[i] + base_s;
        off[i] = t;
        cursor[i] = t;
    }
    if (blockIdx.x == SCAN_B - 1 && tid == 0) off[NN] = total_s;
}

// ---- K4: fill CSR (src only; tgt implicit in bucket) ----
__global__ __launch_bounds__(256) void fill_kernel(
    const int* __restrict__ tgt, const int* __restrict__ src,
    int* __restrict__ cursor, int* __restrict__ edge_src)
{
    int e = blockIdx.x * 256 + threadIdx.x;
    if (e >= NE) return;
    int t = tgt[e];
    int pos = atomicAdd(cursor + t, 1);
    edge_src[pos] = src[e];
}

// ---- K5: fused attention, ONE wave per node (4 nodes/block, no LDS, no
// barriers). All loop bounds forced wave-uniform via readfirstlane; gather
// row index via v_readlane -> SGPR so the 64-bit address math runs on the
// SALU pipe and the gather is one dwordx2 with a precomputed lane offset.
// All cross-lane traffic is immediate-pattern ds_swizzle (no index math).
// Tail edges neutralized by a single p=0 cndmask; ss accumulated own-edge
// per lane (1 add/batch) and tree-reduced once at the end. ----
__global__ __launch_bounds__(256) void attn_kernel(
    const int* __restrict__ off, const int* __restrict__ edge_src,
    const unsigned short* __restrict__ qvb, const unsigned short* __restrict__ kb,
    unsigned short* __restrict__ aggb)
{
    const int tid = threadIdx.x;
    const int lane = tid & 63;
    const int node = blockIdx.x * 4 + (tid >> 6);
    if (node >= NN) return;

    const int base = __builtin_amdgcn_readfirstlane(off[node]);
    const int deg  = __builtin_amdgcn_readfirstlane(off[node + 1]) - base;

    unsigned kw = *(const unsigned*)(kb + (size_t)node * DIM + 2 * lane);
    const float klo = blo(kw), khi = bhi(kw);
    const int j = lane & 7;             // position within 8-lane head group

    float ax = 0.f, ay = 0.f, ss = 0.f;

    for (int c0 = 0; c0 < deg; c0 += 64) {
        const int nchunk = min(deg - c0, 64);                    // uniform
        int srcv = edge_src[base + c0 + min(lane, nchunk - 1)];  // coalesced
        for (int b = 0; b < nchunk; b += 8) {
            const int nb = min(nchunk - b, 8);                   // uniform
            uint2 qv[8];
#pragma unroll
            for (int i = 0; i < 8; ++i) {
                int si = __builtin_amdgcn_readlane(srcv, min(b + i, nchunk - 1));
                qv[i] = ((const uint2*)(qvb + (size_t)si * QVROW))[lane];
            }
            float part[8];
#pragma unroll
            for (int i = 0; i < 8; ++i)
                part[i] = blo(qv[i].x) * klo + bhi(qv[i].x) * khi;
            // stage 1 (xor 1): pairs (0,1)(2,3)(4,5)(6,7)
            float r1[4];
#pragma unroll
            for (int t = 0; t < 4; ++t) {
                float keep = (j & 1) ? part[2 * t + 1] : part[2 * t];
                float send = (j & 1) ? part[2 * t]     : part[2 * t + 1];
                r1[t] = keep + swz<0x041F>(send);
            }
            // stage 2 (xor 2)
            float r2[2];
#pragma unroll
            for (int u = 0; u < 2; ++u) {
                float keep = (j & 2) ? r1[2 * u + 1] : r1[2 * u];
                float send = (j & 2) ? r1[2 * u]     : r1[2 * u + 1];
                r2[u] = keep + swz<0x081F>(send);
            }
            // stage 3 (xor 4): lane j now holds edge (b+j)'s full dot
            float keep = (j & 4) ? r2[1] : r2[0];
            float send = (j & 4) ? r2[0] : r2[1];
            float tot = keep + swz<0x101F>(send);
            float p = (j < nb) ? __expf(tot * 0.25f) : 0.f;   // 1/sqrt(HD); tail -> 0
            ss += p;                                           // own edge only
            // broadcast p within the head group ((lane&0x18)|i) and accumulate v
#define ACC(i) { float pi = swz<((i) << 5) | 0x18>(p); unsigned vv = qv[i].y; \
                 ax += pi * blo(vv); ay += pi * bhi(vv); }
            ACC(0) ACC(1) ACC(2) ACC(3) ACC(4) ACC(5) ACC(6) ACC(7)
#undef ACC
        }
    }
    // reduce ss across the 8-lane head group
    ss += swz<0x041F>(ss);
    ss += swz<0x081F>(ss);
    ss += swz<0x101F>(ss);

    unsigned* ap = (unsigned*)(aggb + (size_t)node * DIM + 2 * lane);
    if (deg == 0) {
        *ap = 0u;
    } else {
        float inv = 1.f / ss;
        *ap = (unsigned)f2b(ax * inv) | ((unsigned)f2b(ay * inv) << 16);
    }
}

// ---- K6: out = agg @ Wo.T + bo via MFMA, Wo staged in LDS, fp32 out ----
__global__ __launch_bounds__(256) void outproj_mfma_kernel(
    const unsigned short* __restrict__ aggb, const unsigned short* __restrict__ Wob,
    const float* __restrict__ bo, float* __restrict__ out)
{
    __shared__ unsigned short Wl[DIM * LROW];
    const int tid = threadIdx.x;
    const int lane = tid & 63;
    const int warp = tid >> 6;
    const int m = lane & 15;
    const int quad = lane >> 4;

#pragma unroll
    for (int it = 0; it < 8; ++it) {
        int chunk = it * 256 + tid;
        int row = chunk >> 4, c8 = chunk & 15;
        *(uint4*)(Wl + row * LROW + c8 * 8) = ((const uint4*)Wob)[chunk];
    }
    __syncthreads();

    const int rt = blockIdx.x * 4 + warp;
    if (rt >= NTILE) return;
    const int r0 = rt * 16;

    v8s a[4];
#pragma unroll
    for (int kt = 0; kt < 4; ++kt)
        a[kt] = *(const v8s*)(aggb + (size_t)(r0 + m) * DIM + kt * 32 + quad * 8);

#pragma unroll
    for (int nt = 0; nt < 8; ++nt) {
        v4f c = {0.f, 0.f, 0.f, 0.f};
#pragma unroll
        for (int kt = 0; kt < 4; ++kt) {
            v8s b = *(const v8s*)(Wl + (nt * 16 + m) * LROW + kt * 32 + quad * 8);
            c = __builtin_amdgcn_mfma_f32_16x16x32_bf16(a[kt], b, c, 0, 0, 0);
        }
        int col = nt * 16 + m;
        float bias = bo[col];
#pragma unroll
        for (int i = 0; i < 4; ++i) {
            int row = r0 + quad * 4 + i;
            out[(size_t)row * DIM + col] = c[i] + bias;
        }
    }
}

extern "C" void kernel_launch(void* const* d_in, const int* in_sizes, int n_in,
                              void* d_out, int out_size, void* d_ws, size_t ws_size,
                              hipStream_t stream) {
    const float* x  = (const float*)d_in[0];
    const int*   ei = (const int*)d_in[1];      // [2, NE]: row0 = tgt, row1 = src
    const float* Wq = (const float*)d_in[2];
    const float* bq = (const float*)d_in[3];
    const float* Wk = (const float*)d_in[4];
    const float* bk = (const float*)d_in[5];
    const float* Wv = (const float*)d_in[6];
    const float* bv = (const float*)d_in[7];
    const float* Wo = (const float*)d_in[8];
    const float* bo = (const float*)d_in[9];

    const int* tgt = ei;
    const int* src = ei + NE;

    char* ws = (char*)d_ws;
    const size_t SZ_QV = (size_t)NN * QVROW * 2;    // 25.6 MB interleaved q+v
    const size_t SZ_BF = (size_t)NN * DIM * 2;      // 12.8 MB

    unsigned short* qvb  = (unsigned short*)(ws);
    unsigned short* kb   = (unsigned short*)(ws + SZ_QV);
    unsigned short* aggb = (unsigned short*)(ws + SZ_QV + SZ_BF);
    unsigned short* Wb   = (unsigned short*)(ws + SZ_QV + 2 * SZ_BF);  // 4 mats, 128 KB

    char* wi = ws + SZ_QV + 2 * SZ_BF + (size_t)4 * DIM * DIM * 2;
    int* cnt      = (int*)(wi);
    int* off      = (int*)(wi + (size_t)NN * 4);
    int* cursor   = (int*)(wi + (size_t)(2 * NN + 1) * 4);
    int* edge_src = (int*)(wi + (size_t)(3 * NN + 1) * 4);
    int* bsum     = (int*)(wi + (size_t)(3 * NN + 1) * 4 + (size_t)NE * 4);

    const int conv_blocks = (NW4 + NC4 + 255) / 256;
    const int edge_blocks = (NE + 255) / 256;  // 3125

    convert_kernel<<<conv_blocks, 256, 0, stream>>>(Wq, Wk, Wv, Wo, Wb, cnt);
    qkv_mfma_kernel<<<TPB, 256, 0, stream>>>(x, Wb, bq, bk, bv, qvb, kb, tgt, cnt);
    scan1_kernel<<<SCAN_B, 256, 0, stream>>>(cnt, off, bsum);
    scan23_kernel<<<SCAN_B, 256, 0, stream>>>(bsum, off, cursor);
    fill_kernel<<<edge_blocks, 256, 0, stream>>>(tgt, src, cursor, edge_src);
    attn_kernel<<<(NN + 3) / 4, 256, 0, stream>>>(off, edge_src, qvb, kb, aggb);
    outproj_mfma_kernel<<<TPB, 256, 0, stream>>>(
        aggb, Wb + (size_t)3 * DIM * DIM, bo, (float*)d_out);
}

// Round 3
// 248.382 us; speedup vs baseline: 1.0191x; 1.0191x over previous
//
#include <hip/hip_runtime.h>
#include <math.h>

#define NN 50000
#define NE 800000
#define DIM 128
#define NH 8
#define HD 16
#define NTILE 3125            // NN/16 exactly
#define TPB 782               // ceil(NTILE/4) tile-groups per matrix
#define LROW 136              // LDS row stride in shorts (128 + 8 pad)
#define QVROW 256             // interleaved qv row: 256 shorts = 512 B
#define SCAN_B 196            // ceil(NN/256)

typedef short v8s __attribute__((ext_vector_type(8)));
typedef float v4f __attribute__((ext_vector_type(4)));

__device__ __forceinline__ unsigned short f2b(float f) {
    unsigned u = __float_as_uint(f);
    u = (u + 0x7fffu + ((u >> 16) & 1u)) >> 16;   // round-to-nearest-even
    return (unsigned short)u;
}
__device__ __forceinline__ float blo(unsigned w) { return __uint_as_float(w << 16); }
__device__ __forceinline__ float bhi(unsigned w) { return __uint_as_float(w & 0xffff0000u); }

// immediate-pattern lane swizzle (BitMode): src = ((lane & and) | or) ^ xor, per 32-half
template<int PAT>
__device__ __forceinline__ float swz(float x) {
    return __int_as_float(__builtin_amdgcn_ds_swizzle(__float_as_int(x), PAT));
}

// ---- K0: convert W{q,k,v,o} -> bf16 packed; zero cnt ----
#define NW4 (4 * DIM * DIM / 4)     // 16384 float4 of W
#define NC4 ((NN + 3) / 4)          // 12500 int4 of cnt
__global__ __launch_bounds__(256) void convert_kernel(
    const float* __restrict__ Wq, const float* __restrict__ Wk,
    const float* __restrict__ Wv, const float* __restrict__ Wo,
    unsigned short* __restrict__ Wb, int* __restrict__ cnt)
{
    int i = blockIdx.x * 256 + threadIdx.x;
    if (i < NW4) {
        int mat = i >> 12;            // 4096 float4 per matrix
        int off = i & 4095;
        const float* Wsrc = (mat == 0) ? Wq : (mat == 1) ? Wk : (mat == 2) ? Wv : Wo;
        float4 f = ((const float4*)Wsrc)[off];
        uint2 o;
        o.x = (unsigned)f2b(f.x) | ((unsigned)f2b(f.y) << 16);
        o.y = (unsigned)f2b(f.z) | ((unsigned)f2b(f.w) << 16);
        ((uint2*)(Wb + (size_t)mat * DIM * DIM))[off] = o;
    } else if (i < NW4 + NC4) {
        ((int4*)cnt)[i - NW4] = make_int4(0, 0, 0, 0);
    }
}

// ---- K1: QKV via MFMA (+ folded edge histogram). One matrix per block
// (3*TPB grid: latency-bound kernel -> parallelism beats x-reuse; x is
// L3-resident anyway). Epilogue: partner-lane ds_swizzle pairs adjacent
// bf16 cols into ONE aligned dword store (even lanes store rows 0-1 of the
// quad, odd lanes rows 2-3) -> halves store count, kills sub-dword stores. ----
__global__ __launch_bounds__(256) void qkv_mfma_kernel(
    const float* __restrict__ x, const unsigned short* __restrict__ Wb,
    const float* __restrict__ bq, const float* __restrict__ bk, const float* __restrict__ bv,
    unsigned short* __restrict__ qvb, unsigned short* __restrict__ kb,
    const int* __restrict__ tgt, int* __restrict__ cnt)
{
    __shared__ unsigned short Wl[DIM * LROW];   // 34816 B
    const int mat = blockIdx.x / TPB;           // 0=q, 1=k, 2=v
    const int tg  = blockIdx.x % TPB;
    const int tid = threadIdx.x;
    const int lane = tid & 63;
    const int warp = tid >> 6;
    const int m = lane & 15;
    const int quad = lane >> 4;

    // folded histogram: grid-stride over edges (fire-and-forget atomics)
    const int gsize = 3 * TPB * 256;
    for (int e = blockIdx.x * 256 + tid; e < NE; e += gsize)
        atomicAdd(cnt + tgt[e], 1);

    const unsigned short* Wg = Wb + (size_t)mat * DIM * DIM;
#pragma unroll
    for (int it = 0; it < 8; ++it) {
        int chunk = it * 256 + tid;           // 0..2047
        int row = chunk >> 4, c8 = chunk & 15;
        *(uint4*)(Wl + row * LROW + c8 * 8) = ((const uint4*)Wg)[chunk];
    }
    __syncthreads();

    const int rt = tg * 4 + warp;
    if (rt >= NTILE) return;
    const int r0 = rt * 16;

    const float* bias_p = (mat == 0) ? bq : (mat == 1) ? bk : bv;

    v8s a[4];
#pragma unroll
    for (int kt = 0; kt < 4; ++kt) {
        const float4* xr = (const float4*)(x + (size_t)(r0 + m) * DIM + kt * 32 + quad * 8);
        float4 f0 = xr[0], f1 = xr[1];
        v8s t;
        t[0] = (short)f2b(f0.x); t[1] = (short)f2b(f0.y);
        t[2] = (short)f2b(f0.z); t[3] = (short)f2b(f0.w);
        t[4] = (short)f2b(f1.x); t[5] = (short)f2b(f1.y);
        t[6] = (short)f2b(f1.z); t[7] = (short)f2b(f1.w);
        a[kt] = t;
    }

    const int i0 = (lane & 1) ? 2 : 0;        // which two rows this lane stores

#pragma unroll
    for (int nt = 0; nt < 8; ++nt) {
        v4f c = {0.f, 0.f, 0.f, 0.f};
#pragma unroll
        for (int kt = 0; kt < 4; ++kt) {
            v8s b = *(const v8s*)(Wl + (nt * 16 + m) * LROW + kt * 32 + quad * 8);
            c = __builtin_amdgcn_mfma_f32_16x16x32_bf16(a[kt], b, c, 0, 0, 0);
        }
        int col = nt * 16 + m;           // C/D: col = lane&15
        float bias = bias_p[col];
        // pack (col, col^1) bf16 pair via partner-lane swizzle; keep the two
        // rows this lane is responsible for (even: i=0,1; odd: i=2,3)
        unsigned w0 = 0, w1 = 0;
#pragma unroll
        for (int i = 0; i < 4; ++i) {
            unsigned own  = (unsigned)f2b(c[i] + bias);
            unsigned part = (unsigned)__builtin_amdgcn_ds_swizzle((int)own, 0x041F) & 0xffffu;
            unsigned w = (lane & 1) ? (part | (own << 16)) : (own | (part << 16));
            if (i == i0)     w0 = w;
            if (i == i0 + 1) w1 = w;
        }
        int colb = nt * 16 + (m & ~1);   // pair-base col (dword-aligned)
        int rowa = r0 + quad * 4 + i0;
        if (mat == 1) {
            *(unsigned*)(kb + (size_t)rowa * DIM + colb)       = w0;
            *(unsigned*)(kb + (size_t)(rowa + 1) * DIM + colb) = w1;
        } else {
            int pos = colb * 2 + ((mat == 2) ? 2 : 0);   // interleaved qv layout
            *(unsigned*)(qvb + (size_t)rowa * QVROW + pos)       = w0;
            *(unsigned*)(qvb + (size_t)(rowa + 1) * QVROW + pos) = w1;
        }
    }
}

// ---- K2: per-block (256-elem) local exclusive scan + block sums ----
__global__ __launch_bounds__(256) void scan1_kernel(
    const int* __restrict__ cnt, int* __restrict__ off, int* __restrict__ bsum)
{
    __shared__ int ws4[4];
    const int tid = threadIdx.x, lane = tid & 63, wid = tid >> 6;
    int i = blockIdx.x * 256 + tid;
    int v0 = (i < NN) ? cnt[i] : 0;
    int incl = v0;
#pragma unroll
    for (int d = 1; d < 64; d <<= 1) {
        int t = __shfl_up(incl, d);
        if (lane >= d) incl += t;
    }
    if (lane == 63) ws4[wid] = incl;
    __syncthreads();
    int wexcl = 0;
#pragma unroll
    for (int t = 0; t < 3; ++t) if (t < wid) wexcl += ws4[t];
    if (i < NN) off[i] = wexcl + incl - v0;
    if (tid == 255) bsum[blockIdx.x] = wexcl + incl;
}

// ---- K3: each block scans all 196 block sums (redundantly), adds its own
// base to off, inits cursor; last block writes off[NN] = total. ----
__global__ __launch_bounds__(256) void scan23_kernel(
    const int* __restrict__ bsum, int* __restrict__ off, int* __restrict__ cursor)
{
    __shared__ int ws4[4];
    __shared__ int base_s, total_s;
    const int tid = threadIdx.x, lane = tid & 63, wid = tid >> 6;
    int v0 = (tid < SCAN_B) ? bsum[tid] : 0;
    int incl = v0;
#pragma unroll
    for (int d = 1; d < 64; d <<= 1) {
        int t = __shfl_up(incl, d);
        if (lane >= d) incl += t;
    }
    if (lane == 63) ws4[wid] = incl;
    __syncthreads();
    int wexcl = 0;
#pragma unroll
    for (int t = 0; t < 3; ++t) if (t < wid) wexcl += ws4[t];
    int excl = wexcl + incl - v0;
    if (tid == blockIdx.x) base_s = excl;
    if (tid == SCAN_B - 1) total_s = excl + v0;
    __syncthreads();
    int i = blockIdx.x * 256 + tid;
    if (i < NN) {
        int t = off[i] + base_s;
        off[i] = t;
        cursor[i] = t;
    }
    if (blockIdx.x == SCAN_B - 1 && tid == 0) off[NN] = total_s;
}

// ---- K4: fill CSR (src only; tgt implicit in bucket) ----
__global__ __launch_bounds__(256) void fill_kernel(
    const int* __restrict__ tgt, const int* __restrict__ src,
    int* __restrict__ cursor, int* __restrict__ edge_src)
{
    int e = blockIdx.x * 256 + threadIdx.x;
    if (e >= NE) return;
    int t = tgt[e];
    int pos = atomicAdd(cursor + t, 1);
    edge_src[pos] = src[e];
}

// ---- K5: fused attention, ONE wave per node (4 nodes/block, no LDS, no
// barriers). All loop bounds forced wave-uniform via readfirstlane; gather
// row index via v_readlane -> SGPR so the 64-bit address math runs on the
// SALU pipe and the gather is one dwordx2 with a precomputed lane offset.
// All cross-lane traffic is immediate-pattern ds_swizzle (no index math).
// Tail edges neutralized by a single p=0 cndmask; ss accumulated own-edge
// per lane (1 add/batch) and tree-reduced once at the end. ----
__global__ __launch_bounds__(256) void attn_kernel(
    const int* __restrict__ off, const int* __restrict__ edge_src,
    const unsigned short* __restrict__ qvb, const unsigned short* __restrict__ kb,
    unsigned short* __restrict__ aggb)
{
    const int tid = threadIdx.x;
    const int lane = tid & 63;
    const int node = blockIdx.x * 4 + (tid >> 6);
    if (node >= NN) return;

    const int base = __builtin_amdgcn_readfirstlane(off[node]);
    const int deg  = __builtin_amdgcn_readfirstlane(off[node + 1]) - base;

    unsigned kw = *(const unsigned*)(kb + (size_t)node * DIM + 2 * lane);
    const float klo = blo(kw), khi = bhi(kw);
    const int j = lane & 7;             // position within 8-lane head group

    float ax = 0.f, ay = 0.f, ss = 0.f;

    for (int c0 = 0; c0 < deg; c0 += 64) {
        const int nchunk = min(deg - c0, 64);                    // uniform
        int srcv = edge_src[base + c0 + min(lane, nchunk - 1)];  // coalesced
        for (int b = 0; b < nchunk; b += 8) {
            const int nb = min(nchunk - b, 8);                   // uniform
            uint2 qv[8];
#pragma unroll
            for (int i = 0; i < 8; ++i) {
                int si = __builtin_amdgcn_readlane(srcv, min(b + i, nchunk - 1));
                qv[i] = ((const uint2*)(qvb + (size_t)si * QVROW))[lane];
            }
            float part[8];
#pragma unroll
            for (int i = 0; i < 8; ++i)
                part[i] = blo(qv[i].x) * klo + bhi(qv[i].x) * khi;
            // stage 1 (xor 1): pairs (0,1)(2,3)(4,5)(6,7)
            float r1[4];
#pragma unroll
            for (int t = 0; t < 4; ++t) {
                float keep = (j & 1) ? part[2 * t + 1] : part[2 * t];
                float send = (j & 1) ? part[2 * t]     : part[2 * t + 1];
                r1[t] = keep + swz<0x041F>(send);
            }
            // stage 2 (xor 2)
            float r2[2];
#pragma unroll
            for (int u = 0; u < 2; ++u) {
                float keep = (j & 2) ? r1[2 * u + 1] : r1[2 * u];
                float send = (j & 2) ? r1[2 * u]     : r1[2 * u + 1];
                r2[u] = keep + swz<0x081F>(send);
            }
            // stage 3 (xor 4): lane j now holds edge (b+j)'s full dot
            float keep = (j & 4) ? r2[1] : r2[0];
            float send = (j & 4) ? r2[0] : r2[1];
            float tot = keep + swz<0x101F>(send);
            float p = (j < nb) ? __expf(tot * 0.25f) : 0.f;   // 1/sqrt(HD); tail -> 0
            ss += p;                                           // own edge only
            // broadcast p within the head group ((lane&0x18)|i) and accumulate v
#define ACC(i) { float pi = swz<((i) << 5) | 0x18>(p); unsigned vv = qv[i].y; \
                 ax += pi * blo(vv); ay += pi * bhi(vv); }
            ACC(0) ACC(1) ACC(2) ACC(3) ACC(4) ACC(5) ACC(6) ACC(7)
#undef ACC
        }
    }
    // reduce ss across the 8-lane head group
    ss += swz<0x041F>(ss);
    ss += swz<0x081F>(ss);
    ss += swz<0x101F>(ss);

    unsigned* ap = (unsigned*)(aggb + (size_t)node * DIM + 2 * lane);
    if (deg == 0) {
        *ap = 0u;
    } else {
        float inv = 1.f / ss;
        *ap = (unsigned)f2b(ax * inv) | ((unsigned)f2b(ay * inv) << 16);
    }
}

// ---- K6: out = agg @ Wo.T + bo via MFMA, Wo staged in LDS, fp32 out ----
__global__ __launch_bounds__(256) void outproj_mfma_kernel(
    const unsigned short* __restrict__ aggb, const unsigned short* __restrict__ Wob,
    const float* __restrict__ bo, float* __restrict__ out)
{
    __shared__ unsigned short Wl[DIM * LROW];
    const int tid = threadIdx.x;
    const int lane = tid & 63;
    const int warp = tid >> 6;
    const int m = lane & 15;
    const int quad = lane >> 4;

#pragma unroll
    for (int it = 0; it < 8; ++it) {
        int chunk = it * 256 + tid;
        int row = chunk >> 4, c8 = chunk & 15;
        *(uint4*)(Wl + row * LROW + c8 * 8) = ((const uint4*)Wob)[chunk];
    }
    __syncthreads();

    const int rt = blockIdx.x * 4 + warp;
    if (rt >= NTILE) return;
    const int r0 = rt * 16;

    v8s a[4];
#pragma unroll
    for (int kt = 0; kt < 4; ++kt)
        a[kt] = *(const v8s*)(aggb + (size_t)(r0 + m) * DIM + kt * 32 + quad * 8);

#pragma unroll
    for (int nt = 0; nt < 8; ++nt) {
        v4f c = {0.f, 0.f, 0.f, 0.f};
#pragma unroll
        for (int kt = 0; kt < 4; ++kt) {
            v8s b = *(const v8s*)(Wl + (nt * 16 + m) * LROW + kt * 32 + quad * 8);
            c = __builtin_amdgcn_mfma_f32_16x16x32_bf16(a[kt], b, c, 0, 0, 0);
        }
        int col = nt * 16 + m;
        float bias = bo[col];
#pragma unroll
        for (int i = 0; i < 4; ++i) {
            int row = r0 + quad * 4 + i;
            out[(size_t)row * DIM + col] = c[i] + bias;
        }
    }
}

extern "C" void kernel_launch(void* const* d_in, const int* in_sizes, int n_in,
                              void* d_out, int out_size, void* d_ws, size_t ws_size,
                              hipStream_t stream) {
    const float* x  = (const float*)d_in[0];
    const int*   ei = (const int*)d_in[1];      // [2, NE]: row0 = tgt, row1 = src
    const float* Wq = (const float*)d_in[2];
    const float* bq = (const float*)d_in[3];
    const float* Wk = (const float*)d_in[4];
    const float* bk = (const float*)d_in[5];
    const float* Wv = (const float*)d_in[6];
    const float* bv = (const float*)d_in[7];
    const float* Wo = (const float*)d_in[8];
    const float* bo = (const float*)d_in[9];

    const int* tgt = ei;
    const int* src = ei + NE;

    char* ws = (char*)d_ws;
    const size_t SZ_QV = (size_t)NN * QVROW * 2;    // 25.6 MB interleaved q+v
    const size_t SZ_BF = (size_t)NN * DIM * 2;      // 12.8 MB

    unsigned short* qvb  = (unsigned short*)(ws);
    unsigned short* kb   = (unsigned short*)(ws + SZ_QV);
    unsigned short* aggb = (unsigned short*)(ws + SZ_QV + SZ_BF);
    unsigned short* Wb   = (unsigned short*)(ws + SZ_QV + 2 * SZ_BF);  // 4 mats, 128 KB

    char* wi = ws + SZ_QV + 2 * SZ_BF + (size_t)4 * DIM * DIM * 2;
    int* cnt      = (int*)(wi);
    int* off      = (int*)(wi + (size_t)NN * 4);
    int* cursor   = (int*)(wi + (size_t)(2 * NN + 1) * 4);
    int* edge_src = (int*)(wi + (size_t)(3 * NN + 1) * 4);
    int* bsum     = (int*)(wi + (size_t)(3 * NN + 1) * 4 + (size_t)NE * 4);

    const int conv_blocks = (NW4 + NC4 + 255) / 256;
    const int edge_blocks = (NE + 255) / 256;  // 3125

    convert_kernel<<<conv_blocks, 256, 0, stream>>>(Wq, Wk, Wv, Wo, Wb, cnt);
    qkv_mfma_kernel<<<3 * TPB, 256, 0, stream>>>(x, Wb, bq, bk, bv, qvb, kb, tgt, cnt);
    scan1_kernel<<<SCAN_B, 256, 0, stream>>>(cnt, off, bsum);
    scan23_kernel<<<SCAN_B, 256, 0, stream>>>(bsum, off, cursor);
    fill_kernel<<<edge_blocks, 256, 0, stream>>>(tgt, src, cursor, edge_src);
    attn_kernel<<<(NN + 3) / 4, 256, 0, stream>>>(off, edge_src, qvb, kb, aggb);
    outproj_mfma_kernel<<<TPB, 256, 0, stream>>>(
        aggb, Wb + (size_t)3 * DIM * DIM, bo, (float*)d_out);
}